// Round 15
// baseline (316.623 us; speedup 1.0000x reference)
//
#include <hip/hip_runtime.h>
#include <hip/hip_bf16.h>

#define N_NODES   50000
#define N_EDGES   800000
#define IN_DIM    64
#define HID       128
#define NUM_GRAPHS 256
#define NBUCK     196     // ceil(50000/256) buckets of 256 nodes
#define BCAP      8192    // fixed ebuf capacity per bucket (avg fill 4082)

typedef __bf16 bf16x8 __attribute__((ext_vector_type(8)));
typedef unsigned short u16x8 __attribute__((ext_vector_type(8)));
typedef float f32x4 __attribute__((ext_vector_type(4)));

__device__ __forceinline__ float b2f(unsigned short u) {
    return __uint_as_float(((unsigned int)u) << 16);
}
__device__ __forceinline__ unsigned short f2b(float f) {
    unsigned int x = __float_as_uint(f);
    x = (x + 0x7fffu + ((x >> 16) & 1u)) >> 16;   // RNE
    return (unsigned short)x;
}

__global__ void diag_kernel(unsigned short* out, unsigned short pat) {
    out[threadIdx.x] = pat;
}

// ---------------- mega preprocess ----------------
// blocks 0..351: GIN weight reorder; 352..547: graph ranges + pool zero;
// 548..579: head_w1 transpose -> w1t[n][k] bf16; 580: dtype probe + bucket cursor init
__global__ __launch_bounds__(256) void mega_pre_kernel(
    const unsigned short* __restrict__ x,
    const void* w0, const void* w1, const void* w2,
    const void* w3, const void* w4, const void* w5,
    unsigned short* __restrict__ wfbase,
    const int* __restrict__ batch, int* __restrict__ gstart,
    float* __restrict__ psum, unsigned int* __restrict__ pmax,
    const void* hw1, unsigned short* __restrict__ w1t,
    int* __restrict__ bcursor, int* __restrict__ flagp) {
    int b = blockIdx.x;
    int tid = threadIdx.x;

    if (b < 352) {
        __shared__ int cnt;
        if (tid == 0) cnt = 0;
        __syncthreads();
        unsigned short u = x[2 * tid];
        int e = (u >> 7) & 0xff;
        if (e <= 100 || e >= 140) atomicAdd(&cnt, 1);
        __syncthreads();
        int flag = cnt > 64;   // 1 = fp32, 0 = bf16

        int mat, boff;
        if (b < 32) { mat = 0; boff = b; }
        else { mat = 1 + (b - 32) / 64; boff = (b - 32) % 64; }
        const void* W = mat == 0 ? w0 : mat == 1 ? w1 : mat == 2 ? w2
                      : mat == 3 ? w3 : mat == 4 ? w4 : w5;
        int KC = (mat == 0) ? 2 : 4;
        int idx = boff * 256 + tid;
        int j  = idx & 7;
        int l  = (idx >> 3) & 63;
        int tc = idx >> 9;
        int c  = tc % KC;
        int t  = tc / KC;
        int k  = c * 32 + (l >> 4) * 8 + j;
        int n  = t * 16 + (l & 15);
        unsigned short v = flag ? f2b(((const float*)W)[k * 128 + n])
                                : ((const unsigned short*)W)[k * 128 + n];
        wfbase[mat * 16384 + idx] = v;
    } else if (b < 548) {
        int i = (b - 352) * 256 + tid;
        if (i < NUM_GRAPHS * HID) { psum[i] = 0.0f; pmax[i] = 0u; }
        if (i >= N_NODES) return;
        int b1 = batch[i];
        int b0 = (i == 0) ? -1 : batch[i - 1];
        for (int g = b0 + 1; g <= b1; g++) gstart[g] = i;
        if (i == N_NODES - 1)
            for (int g = b1 + 1; g <= NUM_GRAPHS; g++) gstart[g] = N_NODES;
    } else if (b < 580) {
        // head_w1 transpose: w1t[n*256 + k] = hw1[k*128 + n], bf16
        __shared__ int cnt;
        if (tid == 0) cnt = 0;
        __syncthreads();
        unsigned short u = x[2 * tid];
        int e = (u >> 7) & 0xff;
        if (e <= 100 || e >= 140) atomicAdd(&cnt, 1);
        __syncthreads();
        int flag = cnt > 64;
        int base = (b - 548) * 1024;
#pragma unroll
        for (int j = 0; j < 4; j++) {
            int idx = base + j * 256 + tid;   // [0, 32768)
            int n = idx >> 8;
            int k = idx & 255;
            unsigned short v = flag ? f2b(((const float*)hw1)[k * 128 + n])
                                    : ((const unsigned short*)hw1)[k * 128 + n];
            w1t[idx] = v;
        }
    } else {
        if (tid < NBUCK) bcursor[tid] = tid * BCAP;
        __shared__ int cnt;
        if (tid == 0) cnt = 0;
        __syncthreads();
        int c = 0;
        for (int j = 0; j < 16; j++) {
            unsigned short u = x[2 * (tid * 16 + j)];
            int e = (u >> 7) & 0xff;
            if (e <= 100 || e >= 140) c++;
        }
        atomicAdd(&cnt, c);
        __syncthreads();
        if (tid == 0) *flagp = (cnt > 1024) ? 1 : 0;
    }
}

// ---------------- CSR build: scatter into fixed-capacity bucket regions ----------------
__global__ __launch_bounds__(1024) void bscatter_kernel(const int* __restrict__ src,
        const int* __restrict__ dst, int* __restrict__ bcursor,
        unsigned int* __restrict__ ebuf) {
    __shared__ int lcnt[NBUCK];
    __shared__ int lbase[NBUCK];
    __shared__ int lcur[NBUCK];
    int tid = threadIdx.x;
    if (tid < NBUCK) lcnt[tid] = 0;
    __syncthreads();
    int e0 = blockIdx.x * 4096;
    int d[4], s[4];
#pragma unroll
    for (int k = 0; k < 4; k++) {
        int e = e0 + k * 1024 + tid;
        if (e < N_EDGES) {
            d[k] = dst[e]; s[k] = src[e];
            atomicAdd(&lcnt[d[k] >> 8], 1);
        } else d[k] = -1;
    }
    __syncthreads();
    if (tid < NBUCK) {
        int c = lcnt[tid];
        lbase[tid] = c ? atomicAdd(&bcursor[tid], c) : 0;
        lcur[tid] = 0;
    }
    __syncthreads();
#pragma unroll
    for (int k = 0; k < 4; k++) {
        if (d[k] >= 0) {
            int b = d[k] >> 8;
            int p = lbase[b] + atomicAdd(&lcur[b], 1);
            ebuf[p] = ((unsigned int)(d[k] & 255) << 16) | (unsigned int)s[k];
        }
    }
}

// per-bucket counting sort -> compact off + csr; bucket counts/bases derived
// from final cursors via a redundant in-block 196-scan (replaces bscan pass).
__global__ __launch_bounds__(256) void bsort_kernel(const unsigned int* __restrict__ ebuf,
        const int* __restrict__ bcursor, int* __restrict__ off,
        unsigned short* __restrict__ csr) {
    __shared__ int cntA[256];
    __shared__ int sc[256];
    __shared__ int lcnt[256];
    __shared__ int lcur[256];
    int b = blockIdx.x, tid = threadIdx.x;

    // derive per-bucket counts and this bucket's global base
    int v = (tid < NBUCK) ? (bcursor[tid] - tid * BCAP) : 0;
    cntA[tid] = v;
    sc[tid] = v;
    __syncthreads();
    for (int d = 1; d < 256; d <<= 1) {
        int t = (tid >= d) ? sc[tid - d] : 0;
        __syncthreads();
        sc[tid] += t;
        __syncthreads();
    }
    int base = sc[b] - cntA[b];   // exclusive prefix for this bucket
    int cnt  = cntA[b];
    int ebase = b * BCAP;
    __syncthreads();

    lcnt[tid] = 0;
    __syncthreads();
    for (int i = tid; i < cnt; i += 256)
        atomicAdd(&lcnt[ebuf[ebase + i] >> 16], 1);
    __syncthreads();
    int v2 = lcnt[tid];
    sc[tid] = v2;
    __syncthreads();
    for (int d = 1; d < 256; d <<= 1) {
        int t = (tid >= d) ? sc[tid - d] : 0;
        __syncthreads();
        sc[tid] += t;
        __syncthreads();
    }
    int excl = sc[tid] - v2;
    lcur[tid] = excl;
    int node = b * 256 + tid;
    if (node < N_NODES) off[node] = base + excl;
    if (b == 0 && tid == 0) off[N_NODES] = N_EDGES;
    __syncthreads();
    for (int i = tid; i < cnt; i += 256) {
        unsigned int ev = ebuf[ebase + i];
        int p = atomicAdd(&lcur[ev >> 16], 1);
        csr[base + p] = (unsigned short)(ev & 0xffffu);
    }
}

// ---------------- gather layer 0 from raw x ----------------
// 4 nodes/wave (16 lanes each, 4 feats/lane), 4-deep ILP -> 16 outstanding loads.
__global__ __launch_bounds__(256) void gather_x_kernel(const void* __restrict__ x,
        const int* __restrict__ off, const unsigned short* __restrict__ csr,
        unsigned short* __restrict__ z, const int* __restrict__ flagp) {
    int flag = *flagp;
    int wave = threadIdx.x >> 6;
    int lane = threadIdx.x & 63;
    int node = blockIdx.x * 16 + wave * 4 + (lane >> 4);   // grid 3125 exact
    int l = lane & 15;
    int s = off[node], e = off[node + 1];
    float a0, a1, a2, a3;
    float b0 = 0.f, b1 = 0.f, b2 = 0.f, b3 = 0.f;
    float c0 = 0.f, c1 = 0.f, c2 = 0.f, c3 = 0.f;
    float d0 = 0.f, d1 = 0.f, d2 = 0.f, d3 = 0.f;
    if (flag) {
        const float4* xp = (const float4*)x;
        float4 u = xp[(size_t)node * 16 + l];
        a0 = u.x; a1 = u.y; a2 = u.z; a3 = u.w;
        int i = s;
        for (; i + 3 < e; i += 4) {
            float4 v0 = xp[(size_t)csr[i] * 16 + l];
            float4 v1 = xp[(size_t)csr[i + 1] * 16 + l];
            float4 v2 = xp[(size_t)csr[i + 2] * 16 + l];
            float4 v3 = xp[(size_t)csr[i + 3] * 16 + l];
            a0 += v0.x; a1 += v0.y; a2 += v0.z; a3 += v0.w;
            b0 += v1.x; b1 += v1.y; b2 += v1.z; b3 += v1.w;
            c0 += v2.x; c1 += v2.y; c2 += v2.z; c3 += v2.w;
            d0 += v3.x; d1 += v3.y; d2 += v3.z; d3 += v3.w;
        }
        for (; i < e; i++) {
            float4 v = xp[(size_t)csr[i] * 16 + l];
            a0 += v.x; a1 += v.y; a2 += v.z; a3 += v.w;
        }
    } else {
        const ushort4* xp = (const ushort4*)x;
        ushort4 u = xp[(size_t)node * 16 + l];
        a0 = b2f(u.x); a1 = b2f(u.y); a2 = b2f(u.z); a3 = b2f(u.w);
        int i = s;
        for (; i + 3 < e; i += 4) {
            ushort4 v0 = xp[(size_t)csr[i] * 16 + l];
            ushort4 v1 = xp[(size_t)csr[i + 1] * 16 + l];
            ushort4 v2 = xp[(size_t)csr[i + 2] * 16 + l];
            ushort4 v3 = xp[(size_t)csr[i + 3] * 16 + l];
            a0 += b2f(v0.x); a1 += b2f(v0.y); a2 += b2f(v0.z); a3 += b2f(v0.w);
            b0 += b2f(v1.x); b1 += b2f(v1.y); b2 += b2f(v1.z); b3 += b2f(v1.w);
            c0 += b2f(v2.x); c1 += b2f(v2.y); c2 += b2f(v2.z); c3 += b2f(v2.w);
            d0 += b2f(v3.x); d1 += b2f(v3.y); d2 += b2f(v3.z); d3 += b2f(v3.w);
        }
        for (; i < e; i++) {
            ushort4 v = xp[(size_t)csr[i] * 16 + l];
            a0 += b2f(v.x); a1 += b2f(v.y); a2 += b2f(v.z); a3 += b2f(v.w);
        }
    }
    ushort4 o;
    o.x = f2b(a0 + b0 + c0 + d0);
    o.y = f2b(a1 + b1 + c1 + d1);
    o.z = f2b(a2 + b2 + c2 + d2);
    o.w = f2b(a3 + b3 + c3 + d3);
    ((ushort4*)z)[(size_t)node * 16 + l] = o;
}

// ---------------- gather (128-dim bf16): 4 nodes/wave, 8 feats/lane, 4-deep ILP ----------------
__global__ __launch_bounds__(256) void gather128_kernel(const unsigned short* __restrict__ h,
        const int* __restrict__ off, const unsigned short* __restrict__ csr,
        unsigned short* __restrict__ z) {
    int wave = threadIdx.x >> 6;
    int lane = threadIdx.x & 63;
    int node = blockIdx.x * 16 + wave * 4 + (lane >> 4);   // grid 3125 exact
    int l = lane & 15;
    int s = off[node], e = off[node + 1];
    const u16x8* hp = (const u16x8*)h;
    u16x8 u = hp[(size_t)node * 16 + l];
    float a[8], b[8], c[8], d[8];
#pragma unroll
    for (int j = 0; j < 8; j++) { a[j] = b2f(u[j]); b[j] = 0.f; c[j] = 0.f; d[j] = 0.f; }
    int i = s;
    for (; i + 3 < e; i += 4) {
        u16x8 v0 = hp[(size_t)csr[i] * 16 + l];
        u16x8 v1 = hp[(size_t)csr[i + 1] * 16 + l];
        u16x8 v2 = hp[(size_t)csr[i + 2] * 16 + l];
        u16x8 v3 = hp[(size_t)csr[i + 3] * 16 + l];
#pragma unroll
        for (int j = 0; j < 8; j++) {
            a[j] += b2f(v0[j]); b[j] += b2f(v1[j]);
            c[j] += b2f(v2[j]); d[j] += b2f(v3[j]);
        }
    }
    for (; i < e; i++) {
        u16x8 v = hp[(size_t)csr[i] * 16 + l];
#pragma unroll
        for (int j = 0; j < 8; j++) a[j] += b2f(v[j]);
    }
    u16x8 o;
#pragma unroll
    for (int j = 0; j < 8; j++) o[j] = f2b(a[j] + b[j] + c[j] + d[j]);
    ((u16x8*)z)[(size_t)node * 16 + l] = o;
}

// ---------------- fused GIN MLP: 2 waves x 32 rows (B-frag reuse halves weight traffic) ----------------
// POOL=true: skip global h store; stage bf16 h-tile in lds_hi and pool in-block.
template <int K1, bool POOL>
__global__ __launch_bounds__(128) void gin_mlp_kernel(
    const unsigned short* __restrict__ Z,
    const unsigned short* __restrict__ Wf1, const void* __restrict__ bias1,
    const unsigned short* __restrict__ Wf2, const void* __restrict__ bias2,
    unsigned short* __restrict__ Out, int M, const int* __restrict__ flagp,
    const int* __restrict__ batch, float* __restrict__ psum,
    unsigned int* __restrict__ pmax) {
    constexpr int KC1 = K1 / 32;
    __shared__ unsigned short lds_hi[64 * 136];
    __shared__ unsigned short lds_lo[64 * 136];
    __shared__ int batch_lds[64];

    int flag = *flagp;
    int wave = threadIdx.x >> 6;   // 0..1
    int lane = threadIdx.x & 63;
    int m_ = lane & 15;
    int q  = lane >> 4;
    int rowbase = blockIdx.x * 64 + wave * 32;
    int row0 = rowbase + m_;
    int row1 = rowbase + 16 + m_;
    int rowc0 = row0 < M ? row0 : (M - 1);
    int rowc1 = row1 < M ? row1 : (M - 1);

    if constexpr (POOL) {
        if (threadIdx.x < 64) {
            int gr = blockIdx.x * 64 + threadIdx.x;
            batch_lds[threadIdx.x] = gr < M ? batch[gr] : -1;
        }
    }

    const unsigned short* zr0 = Z + (size_t)rowc0 * K1 + q * 8;
    const unsigned short* zr1 = Z + (size_t)rowc1 * K1 + q * 8;
    const unsigned short* wfl1 = Wf1 + lane * 8;
    const unsigned short* wfl2 = Wf2 + lane * 8;

    f32x4 acc[2][8];
#pragma unroll
    for (int g = 0; g < 2; g++)
#pragma unroll
        for (int t = 0; t < 8; t++) acc[g][t] = (f32x4)(0.0f);

    // phase 1: mid = Z @ W1 (B loaded once per (c,t), used for both row groups)
#pragma unroll
    for (int c = 0; c < KC1; c++) {
        bf16x8 a0 = *reinterpret_cast<const bf16x8*>(zr0 + c * 32);
        bf16x8 a1 = *reinterpret_cast<const bf16x8*>(zr1 + c * 32);
#pragma unroll
        for (int t = 0; t < 8; t++) {
            bf16x8 b = *reinterpret_cast<const bf16x8*>(wfl1 + ((t * KC1 + c) << 9));
            acc[0][t] = __builtin_amdgcn_mfma_f32_16x16x32_bf16(a0, b, acc[0][t], 0, 0, 0);
            acc[1][t] = __builtin_amdgcn_mfma_f32_16x16x32_bf16(a1, b, acc[1][t], 0, 0, 0);
        }
    }

    // epilogue 1: +b1, relu, hi/lo split -> LDS (rows wave*32 .. wave*32+31)
#pragma unroll
    for (int g = 0; g < 2; g++)
#pragma unroll
    for (int r = 0; r < 4; r++) {
        int lr = wave * 32 + g * 16 + q * 4 + r;
#pragma unroll
        for (int t = 0; t < 8; t++) {
            int col = t * 16 + m_;
            float bv = flag ? ((const float*)bias1)[col]
                            : b2f(((const unsigned short*)bias1)[col]);
            float v = acc[g][t][r] + bv;
            v = v > 0.0f ? v : 0.0f;
            unsigned short hb = f2b(v);
            lds_hi[lr * 136 + col] = hb;
            lds_lo[lr * 136 + col] = f2b(v - b2f(hb));
        }
    }

#pragma unroll
    for (int g = 0; g < 2; g++)
#pragma unroll
        for (int t = 0; t < 8; t++) acc[g][t] = (f32x4)(0.0f);

    // phase 2: h = mid @ W2 (hi/lo from LDS; B shared across both row groups)
    int l2_0 = wave * 32 + m_;
    int l2_1 = wave * 32 + 16 + m_;
#pragma unroll
    for (int c = 0; c < 4; c++) {
        bf16x8 ahi0 = *reinterpret_cast<const bf16x8*>(&lds_hi[l2_0 * 136 + c * 32 + q * 8]);
        bf16x8 alo0 = *reinterpret_cast<const bf16x8*>(&lds_lo[l2_0 * 136 + c * 32 + q * 8]);
        bf16x8 ahi1 = *reinterpret_cast<const bf16x8*>(&lds_hi[l2_1 * 136 + c * 32 + q * 8]);
        bf16x8 alo1 = *reinterpret_cast<const bf16x8*>(&lds_lo[l2_1 * 136 + c * 32 + q * 8]);
#pragma unroll
        for (int t = 0; t < 8; t++) {
            bf16x8 b = *reinterpret_cast<const bf16x8*>(wfl2 + ((t * 4 + c) << 9));
            acc[0][t] = __builtin_amdgcn_mfma_f32_16x16x32_bf16(ahi0, b, acc[0][t], 0, 0, 0);
            acc[0][t] = __builtin_amdgcn_mfma_f32_16x16x32_bf16(alo0, b, acc[0][t], 0, 0, 0);
            acc[1][t] = __builtin_amdgcn_mfma_f32_16x16x32_bf16(ahi1, b, acc[1][t], 0, 0, 0);
            acc[1][t] = __builtin_amdgcn_mfma_f32_16x16x32_bf16(alo1, b, acc[1][t], 0, 0, 0);
        }
    }

    // epilogue 2
#pragma unroll
    for (int g = 0; g < 2; g++)
#pragma unroll
    for (int r = 0; r < 4; r++) {
        int lr = wave * 32 + g * 16 + q * 4 + r;
        int orow = blockIdx.x * 64 + lr;
#pragma unroll
        for (int t = 0; t < 8; t++) {
            int col = t * 16 + m_;
            float bv = flag ? ((const float*)bias2)[col]
                            : b2f(((const unsigned short*)bias2)[col]);
            float v = acc[g][t][r] + bv;
            v = v > 0.0f ? v : 0.0f;
            if constexpr (POOL) {
                lds_hi[lr * 136 + col] = f2b(v);   // safe: own rows' phase-2 reads done
            } else {
                if (orow < M) Out[(size_t)orow * HID + col] = f2b(v);
            }
        }
    }

    if constexpr (POOL) {
        __syncthreads();
        int f = threadIdx.x;   // 128 threads cover HID exactly
        int cur = -1;
        float sum = 0.0f, mx = 0.0f;
        for (int rrow = 0; rrow < 64; rrow++) {
            int g = batch_lds[rrow];
            if (g < 0) break;   // tail padding
            float v = b2f(lds_hi[rrow * 136 + f]);
            if (g == cur) {
                sum += v;
                mx = fmaxf(mx, v);
            } else {
                if (cur >= 0) {
                    atomicAdd(&psum[cur * HID + f], sum);
                    atomicMax(&pmax[cur * HID + f], __float_as_uint(mx));
                }
                cur = g; sum = v; mx = v;
            }
        }
        if (cur >= 0) {
            atomicAdd(&psum[cur * HID + f], sum);
            atomicMax(&pmax[cur * HID + f], __float_as_uint(mx));
        }
    }
}

// ---------------- head: w1t[n][k] bf16 rows -> vectorized, unrolled dot ----------------
__global__ __launch_bounds__(128) void head_kernel(
    const float* __restrict__ psum, const unsigned int* __restrict__ pmax,
    const int* __restrict__ gstart,
    const unsigned short* __restrict__ w1t,
    const void* __restrict__ b1, const void* __restrict__ w2,
    const void* __restrict__ b2,
    void* __restrict__ out, const int* __restrict__ flagp) {
    int g = blockIdx.x;
    int n = threadIdx.x;
    int flag = *flagp;
    __shared__ float repr[2 * HID];
    __shared__ float red[HID];

    float c = (float)(gstart[g + 1] - gstart[g]);
    float inv = 1.0f / fmaxf(c, 1.0f);
    repr[n]       = psum[g * HID + n] * inv;
    repr[HID + n] = __uint_as_float(pmax[g * HID + n]);
    __syncthreads();

    const u16x8* wp = (const u16x8*)(w1t + n * 256);
    float a0 = 0.f, a1 = 0.f, a2 = 0.f, a3 = 0.f;
#pragma unroll
    for (int c8 = 0; c8 < 32; c8 += 4) {
        u16x8 w0 = wp[c8 + 0];
        u16x8 w1 = wp[c8 + 1];
        u16x8 w2v = wp[c8 + 2];
        u16x8 w3 = wp[c8 + 3];
#pragma unroll
        for (int j = 0; j < 8; j++) {
            a0 += repr[(c8 + 0) * 8 + j] * b2f(w0[j]);
            a1 += repr[(c8 + 1) * 8 + j] * b2f(w1[j]);
            a2 += repr[(c8 + 2) * 8 + j] * b2f(w2v[j]);
            a3 += repr[(c8 + 3) * 8 + j] * b2f(w3[j]);
        }
    }
    float b1v = flag ? ((const float*)b1)[n] : b2f(((const unsigned short*)b1)[n]);
    float acc = a0 + a1 + a2 + a3 + b1v;
    acc = fmaxf(acc, 0.0f);

    float w2s = flag ? ((const float*)w2)[n] : b2f(((const unsigned short*)w2)[n]);
    red[n] = acc * w2s;
    __syncthreads();
    for (int s = 64; s > 0; s >>= 1) {
        if (n < s) red[n] += red[n + s];
        __syncthreads();
    }
    if (n == 0) {
        float b2v = flag ? ((const float*)b2)[0] : b2f(((const unsigned short*)b2)[0]);
        float logit = red[0] + b2v;
        float sv = 1.0f / (1.0f + expf(-logit));
        if (flag) ((float*)out)[g] = sv;
        else      ((unsigned short*)out)[g] = f2b(sv);
    }
}

extern "C" void kernel_launch(void* const* d_in, const int* in_sizes, int n_in,
                              void* d_out, int out_size, void* d_ws, size_t ws_size,
                              hipStream_t stream) {
    const int* edge = (const int*)d_in[1];
    const int* srcv = edge;
    const int* dstv = edge + N_EDGES;
    const int* batch = (const int*)d_in[2];

    char* ws = (char*)d_ws;
    unsigned short* A = (unsigned short*)ws;               // 12.8 MB bf16 h (even)
    unsigned short* B = (unsigned short*)(ws + 12800000);  // 12.8 MB bf16 z / h (odd)
    unsigned int* ebuf = (unsigned int*)(ws + 25600000);   // 6.43 MB bucketed edges
    unsigned short* csr = (unsigned short*)(ws + 32100000);// 1.6 MB
    int* off    = (int*)(ws + 33700000);                   // 50001 ints
    unsigned short* wfbase = (unsigned short*)(ws + 33904000);  // 6 x 32 KB
    float* psum  = (float*)(ws + 34100608);                // 128 KB
    unsigned int* pmax = (unsigned int*)(ws + 34231680);   // 128 KB
    int* bcursor = (int*)(ws + 34362752);                  // 1 KB
    int* gstart  = (int*)(ws + 34363776);                  // 2 KB
    int* flagp   = (int*)(ws + 34365824);
    unsigned short* w1t = (unsigned short*)(ws + 34366848); // 64 KB

    const size_t NEED = 34500000;
    if (ws_size < NEED) {
        unsigned int k = 0;
        while ((((size_t)1) << (k + 1)) <= ws_size && k < 62) k++;
        diag_kernel<<<1, 256, 0, stream>>>((unsigned short*)d_out,
                                           (unsigned short)(0x4000 | (k & 63)));
        return;
    }

    mega_pre_kernel<<<581, 256, 0, stream>>>(
        (const unsigned short*)d_in[0],
        d_in[3], d_in[5], d_in[7], d_in[9], d_in[11], d_in[13], wfbase,
        batch, gstart, psum, pmax, d_in[15], w1t, bcursor, flagp);

    // CSR build: scatter into fixed buckets, then per-bucket sort (no bscan pass)
    const int EB = (N_EDGES + 4095) / 4096;   // 196
    bscatter_kernel<<<EB, 1024, 0, stream>>>(srcv, dstv, bcursor, ebuf);
    bsort_kernel<<<NBUCK, 256, 0, stream>>>(ebuf, bcursor, off, csr);

    const int GEMM_GRID = (N_NODES + 63) / 64;   // 782
    const int GATHER_GRID = N_NODES / 16;        // 3125 (exact)

    // layer 0: 64 -> 128 (x -> B(z) -> A(h1))
    gather_x_kernel<<<GATHER_GRID, 256, 0, stream>>>(d_in[0], off, csr, B, flagp);
    gin_mlp_kernel<64, false><<<GEMM_GRID, 128, 0, stream>>>(
        B, wfbase + 0 * 16384, d_in[4], wfbase + 1 * 16384, d_in[6],
        A, N_NODES, flagp, batch, psum, pmax);

    // layer 1: 128 -> 128 (A -> B(z) -> A)
    gather128_kernel<<<GATHER_GRID, 256, 0, stream>>>(A, off, csr, B);
    gin_mlp_kernel<128, false><<<GEMM_GRID, 128, 0, stream>>>(
        B, wfbase + 2 * 16384, d_in[8], wfbase + 3 * 16384, d_in[10],
        A, N_NODES, flagp, batch, psum, pmax);

    // layer 2: 128 -> 128 (A -> B(z) -> pooled directly, no h3 store)
    gather128_kernel<<<GATHER_GRID, 256, 0, stream>>>(A, off, csr, B);
    gin_mlp_kernel<128, true><<<GEMM_GRID, 128, 0, stream>>>(
        B, wfbase + 4 * 16384, d_in[12], wfbase + 5 * 16384, d_in[14],
        A /*unused*/, N_NODES, flagp, batch, psum, pmax);

    // head
    head_kernel<<<NUM_GRAPHS, 128, 0, stream>>>(psum, pmax, gstart, w1t,
                                                d_in[16], d_in[17], d_in[18],
                                                d_out, flagp);
}

// Round 16
// 307.982 us; speedup vs baseline: 1.0281x; 1.0281x over previous
//
#include <hip/hip_runtime.h>
#include <hip/hip_bf16.h>

#define N_NODES   50000
#define N_EDGES   800000
#define IN_DIM    64
#define HID       128
#define NUM_GRAPHS 256
#define NBUCK     196     // ceil(50000/256) buckets of 256 nodes
#define BCAP      8192    // fixed ebuf capacity per bucket (avg fill 4082)

typedef __bf16 bf16x8 __attribute__((ext_vector_type(8)));
typedef unsigned short u16x8 __attribute__((ext_vector_type(8)));
typedef float f32x4 __attribute__((ext_vector_type(4)));

__device__ __forceinline__ float b2f(unsigned short u) {
    return __uint_as_float(((unsigned int)u) << 16);
}
__device__ __forceinline__ unsigned short f2b(float f) {
    unsigned int x = __float_as_uint(f);
    x = (x + 0x7fffu + ((x >> 16) & 1u)) >> 16;   // RNE
    return (unsigned short)x;
}

__global__ void diag_kernel(unsigned short* out, unsigned short pat) {
    out[threadIdx.x] = pat;
}

// ---------------- mega preprocess ----------------
// blocks 0..351: GIN weight reorder; 352..547: graph ranges + pool zero;
// 548..579: head_w1 transpose -> w1t[n][k] bf16; 580: dtype probe + bucket cursor init
__global__ __launch_bounds__(256) void mega_pre_kernel(
    const unsigned short* __restrict__ x,
    const void* w0, const void* w1, const void* w2,
    const void* w3, const void* w4, const void* w5,
    unsigned short* __restrict__ wfbase,
    const int* __restrict__ batch, int* __restrict__ gstart,
    float* __restrict__ psum, unsigned int* __restrict__ pmax,
    const void* hw1, unsigned short* __restrict__ w1t,
    int* __restrict__ bcursor, int* __restrict__ flagp) {
    int b = blockIdx.x;
    int tid = threadIdx.x;

    if (b < 352) {
        __shared__ int cnt;
        if (tid == 0) cnt = 0;
        __syncthreads();
        unsigned short u = x[2 * tid];
        int e = (u >> 7) & 0xff;
        if (e <= 100 || e >= 140) atomicAdd(&cnt, 1);
        __syncthreads();
        int flag = cnt > 64;   // 1 = fp32, 0 = bf16

        int mat, boff;
        if (b < 32) { mat = 0; boff = b; }
        else { mat = 1 + (b - 32) / 64; boff = (b - 32) % 64; }
        const void* W = mat == 0 ? w0 : mat == 1 ? w1 : mat == 2 ? w2
                      : mat == 3 ? w3 : mat == 4 ? w4 : w5;
        int KC = (mat == 0) ? 2 : 4;
        int idx = boff * 256 + tid;
        int j  = idx & 7;
        int l  = (idx >> 3) & 63;
        int tc = idx >> 9;
        int c  = tc % KC;
        int t  = tc / KC;
        int k  = c * 32 + (l >> 4) * 8 + j;
        int n  = t * 16 + (l & 15);
        unsigned short v = flag ? f2b(((const float*)W)[k * 128 + n])
                                : ((const unsigned short*)W)[k * 128 + n];
        wfbase[mat * 16384 + idx] = v;
    } else if (b < 548) {
        int i = (b - 352) * 256 + tid;
        if (i < NUM_GRAPHS * HID) { psum[i] = 0.0f; pmax[i] = 0u; }
        if (i >= N_NODES) return;
        int b1 = batch[i];
        int b0 = (i == 0) ? -1 : batch[i - 1];
        for (int g = b0 + 1; g <= b1; g++) gstart[g] = i;
        if (i == N_NODES - 1)
            for (int g = b1 + 1; g <= NUM_GRAPHS; g++) gstart[g] = N_NODES;
    } else if (b < 580) {
        // head_w1 transpose: w1t[n*256 + k] = hw1[k*128 + n], bf16
        __shared__ int cnt;
        if (tid == 0) cnt = 0;
        __syncthreads();
        unsigned short u = x[2 * tid];
        int e = (u >> 7) & 0xff;
        if (e <= 100 || e >= 140) atomicAdd(&cnt, 1);
        __syncthreads();
        int flag = cnt > 64;
        int base = (b - 548) * 1024;
#pragma unroll
        for (int j = 0; j < 4; j++) {
            int idx = base + j * 256 + tid;   // [0, 32768)
            int n = idx >> 8;
            int k = idx & 255;
            unsigned short v = flag ? f2b(((const float*)hw1)[k * 128 + n])
                                    : ((const unsigned short*)hw1)[k * 128 + n];
            w1t[idx] = v;
        }
    } else {
        if (tid < NBUCK) bcursor[tid] = tid * BCAP;
        __shared__ int cnt;
        if (tid == 0) cnt = 0;
        __syncthreads();
        int c = 0;
        for (int j = 0; j < 16; j++) {
            unsigned short u = x[2 * (tid * 16 + j)];
            int e = (u >> 7) & 0xff;
            if (e <= 100 || e >= 140) c++;
        }
        atomicAdd(&cnt, c);
        __syncthreads();
        if (tid == 0) *flagp = (cnt > 1024) ? 1 : 0;
    }
}

// ---------------- CSR build: scatter into fixed-capacity bucket regions ----------------
__global__ __launch_bounds__(1024) void bscatter_kernel(const int* __restrict__ src,
        const int* __restrict__ dst, int* __restrict__ bcursor,
        unsigned int* __restrict__ ebuf) {
    __shared__ int lcnt[NBUCK];
    __shared__ int lbase[NBUCK];
    __shared__ int lcur[NBUCK];
    int tid = threadIdx.x;
    if (tid < NBUCK) lcnt[tid] = 0;
    __syncthreads();
    int e0 = blockIdx.x * 4096;
    int d[4], s[4];
#pragma unroll
    for (int k = 0; k < 4; k++) {
        int e = e0 + k * 1024 + tid;
        if (e < N_EDGES) {
            d[k] = dst[e]; s[k] = src[e];
            atomicAdd(&lcnt[d[k] >> 8], 1);
        } else d[k] = -1;
    }
    __syncthreads();
    if (tid < NBUCK) {
        int c = lcnt[tid];
        lbase[tid] = c ? atomicAdd(&bcursor[tid], c) : 0;
        lcur[tid] = 0;
    }
    __syncthreads();
#pragma unroll
    for (int k = 0; k < 4; k++) {
        if (d[k] >= 0) {
            int b = d[k] >> 8;
            int p = lbase[b] + atomicAdd(&lcur[b], 1);
            ebuf[p] = ((unsigned int)(d[k] & 255) << 16) | (unsigned int)s[k];
        }
    }
}

// per-bucket counting sort -> compact off + csr; bucket counts/bases derived
// from final cursors via a redundant in-block 196-scan (replaces bscan pass).
__global__ __launch_bounds__(256) void bsort_kernel(const unsigned int* __restrict__ ebuf,
        const int* __restrict__ bcursor, int* __restrict__ off,
        unsigned short* __restrict__ csr) {
    __shared__ int cntA[256];
    __shared__ int sc[256];
    __shared__ int lcnt[256];
    __shared__ int lcur[256];
    int b = blockIdx.x, tid = threadIdx.x;

    int v = (tid < NBUCK) ? (bcursor[tid] - tid * BCAP) : 0;
    cntA[tid] = v;
    sc[tid] = v;
    __syncthreads();
    for (int d = 1; d < 256; d <<= 1) {
        int t = (tid >= d) ? sc[tid - d] : 0;
        __syncthreads();
        sc[tid] += t;
        __syncthreads();
    }
    int base = sc[b] - cntA[b];   // exclusive prefix for this bucket
    int cnt  = cntA[b];
    int ebase = b * BCAP;
    __syncthreads();

    lcnt[tid] = 0;
    __syncthreads();
    for (int i = tid; i < cnt; i += 256)
        atomicAdd(&lcnt[ebuf[ebase + i] >> 16], 1);
    __syncthreads();
    int v2 = lcnt[tid];
    sc[tid] = v2;
    __syncthreads();
    for (int d = 1; d < 256; d <<= 1) {
        int t = (tid >= d) ? sc[tid - d] : 0;
        __syncthreads();
        sc[tid] += t;
        __syncthreads();
    }
    int excl = sc[tid] - v2;
    lcur[tid] = excl;
    int node = b * 256 + tid;
    if (node < N_NODES) off[node] = base + excl;
    if (b == 0 && tid == 0) off[N_NODES] = N_EDGES;
    __syncthreads();
    for (int i = tid; i < cnt; i += 256) {
        unsigned int ev = ebuf[ebase + i];
        int p = atomicAdd(&lcur[ev >> 16], 1);
        csr[base + p] = (unsigned short)(ev & 0xffffu);
    }
}

// ---------------- gather layer 0 from raw x ----------------
// 4 nodes/wave (16 lanes each, 4 feats/lane), 4-deep ILP -> 16 outstanding loads.
__global__ __launch_bounds__(256) void gather_x_kernel(const void* __restrict__ x,
        const int* __restrict__ off, const unsigned short* __restrict__ csr,
        unsigned short* __restrict__ z, const int* __restrict__ flagp) {
    int flag = *flagp;
    int wave = threadIdx.x >> 6;
    int lane = threadIdx.x & 63;
    int node = blockIdx.x * 16 + wave * 4 + (lane >> 4);   // grid 3125 exact
    int l = lane & 15;
    int s = off[node], e = off[node + 1];
    float a0, a1, a2, a3;
    float b0 = 0.f, b1 = 0.f, b2 = 0.f, b3 = 0.f;
    float c0 = 0.f, c1 = 0.f, c2 = 0.f, c3 = 0.f;
    float d0 = 0.f, d1 = 0.f, d2 = 0.f, d3 = 0.f;
    if (flag) {
        const float4* xp = (const float4*)x;
        float4 u = xp[(size_t)node * 16 + l];
        a0 = u.x; a1 = u.y; a2 = u.z; a3 = u.w;
        int i = s;
        for (; i + 3 < e; i += 4) {
            float4 v0 = xp[(size_t)csr[i] * 16 + l];
            float4 v1 = xp[(size_t)csr[i + 1] * 16 + l];
            float4 v2 = xp[(size_t)csr[i + 2] * 16 + l];
            float4 v3 = xp[(size_t)csr[i + 3] * 16 + l];
            a0 += v0.x; a1 += v0.y; a2 += v0.z; a3 += v0.w;
            b0 += v1.x; b1 += v1.y; b2 += v1.z; b3 += v1.w;
            c0 += v2.x; c1 += v2.y; c2 += v2.z; c3 += v2.w;
            d0 += v3.x; d1 += v3.y; d2 += v3.z; d3 += v3.w;
        }
        for (; i < e; i++) {
            float4 v = xp[(size_t)csr[i] * 16 + l];
            a0 += v.x; a1 += v.y; a2 += v.z; a3 += v.w;
        }
    } else {
        const ushort4* xp = (const ushort4*)x;
        ushort4 u = xp[(size_t)node * 16 + l];
        a0 = b2f(u.x); a1 = b2f(u.y); a2 = b2f(u.z); a3 = b2f(u.w);
        int i = s;
        for (; i + 3 < e; i += 4) {
            ushort4 v0 = xp[(size_t)csr[i] * 16 + l];
            ushort4 v1 = xp[(size_t)csr[i + 1] * 16 + l];
            ushort4 v2 = xp[(size_t)csr[i + 2] * 16 + l];
            ushort4 v3 = xp[(size_t)csr[i + 3] * 16 + l];
            a0 += b2f(v0.x); a1 += b2f(v0.y); a2 += b2f(v0.z); a3 += b2f(v0.w);
            b0 += b2f(v1.x); b1 += b2f(v1.y); b2 += b2f(v1.z); b3 += b2f(v1.w);
            c0 += b2f(v2.x); c1 += b2f(v2.y); c2 += b2f(v2.z); c3 += b2f(v2.w);
            d0 += b2f(v3.x); d1 += b2f(v3.y); d2 += b2f(v3.z); d3 += b2f(v3.w);
        }
        for (; i < e; i++) {
            ushort4 v = xp[(size_t)csr[i] * 16 + l];
            a0 += b2f(v.x); a1 += b2f(v.y); a2 += b2f(v.z); a3 += b2f(v.w);
        }
    }
    ushort4 o;
    o.x = f2b(a0 + b0 + c0 + d0);
    o.y = f2b(a1 + b1 + c1 + d1);
    o.z = f2b(a2 + b2 + c2 + d2);
    o.w = f2b(a3 + b3 + c3 + d3);
    ((ushort4*)z)[(size_t)node * 16 + l] = o;
}

// ---------------- gather (128-dim bf16): 4 nodes/wave, 8 feats/lane, 4-deep ILP ----------------
__global__ __launch_bounds__(256) void gather128_kernel(const unsigned short* __restrict__ h,
        const int* __restrict__ off, const unsigned short* __restrict__ csr,
        unsigned short* __restrict__ z) {
    int wave = threadIdx.x >> 6;
    int lane = threadIdx.x & 63;
    int node = blockIdx.x * 16 + wave * 4 + (lane >> 4);   // grid 3125 exact
    int l = lane & 15;
    int s = off[node], e = off[node + 1];
    const u16x8* hp = (const u16x8*)h;
    u16x8 u = hp[(size_t)node * 16 + l];
    float a[8], b[8], c[8], d[8];
#pragma unroll
    for (int j = 0; j < 8; j++) { a[j] = b2f(u[j]); b[j] = 0.f; c[j] = 0.f; d[j] = 0.f; }
    int i = s;
    for (; i + 3 < e; i += 4) {
        u16x8 v0 = hp[(size_t)csr[i] * 16 + l];
        u16x8 v1 = hp[(size_t)csr[i + 1] * 16 + l];
        u16x8 v2 = hp[(size_t)csr[i + 2] * 16 + l];
        u16x8 v3 = hp[(size_t)csr[i + 3] * 16 + l];
#pragma unroll
        for (int j = 0; j < 8; j++) {
            a[j] += b2f(v0[j]); b[j] += b2f(v1[j]);
            c[j] += b2f(v2[j]); d[j] += b2f(v3[j]);
        }
    }
    for (; i < e; i++) {
        u16x8 v = hp[(size_t)csr[i] * 16 + l];
#pragma unroll
        for (int j = 0; j < 8; j++) a[j] += b2f(v[j]);
    }
    u16x8 o;
#pragma unroll
    for (int j = 0; j < 8; j++) o[j] = f2b(a[j] + b[j] + c[j] + d[j]);
    ((u16x8*)z)[(size_t)node * 16 + l] = o;
}

// ---------------- fused GIN MLP: Out = relu(relu(Z@W1+b1)@W2+b2) ----------------
// 4 waves x 16 rows (R14 config). POOL=true: skip global h store; stage bf16
// h-tile in lds_hi and pool in-block.
template <int K1, bool POOL>
__global__ __launch_bounds__(256) void gin_mlp_kernel(
    const unsigned short* __restrict__ Z,
    const unsigned short* __restrict__ Wf1, const void* __restrict__ bias1,
    const unsigned short* __restrict__ Wf2, const void* __restrict__ bias2,
    unsigned short* __restrict__ Out, int M, const int* __restrict__ flagp,
    const int* __restrict__ batch, float* __restrict__ psum,
    unsigned int* __restrict__ pmax) {
    constexpr int KC1 = K1 / 32;
    __shared__ unsigned short lds_hi[64 * 136];
    __shared__ unsigned short lds_lo[64 * 136];
    __shared__ int batch_lds[64];

    int flag = *flagp;
    int wave = threadIdx.x >> 6;
    int lane = threadIdx.x & 63;
    int m_ = lane & 15;
    int q  = lane >> 4;
    int rowbase = blockIdx.x * 64 + wave * 16;
    int row  = rowbase + m_;
    int rowc = row < M ? row : (M - 1);

    if constexpr (POOL) {
        if (threadIdx.x < 64) {
            int gr = blockIdx.x * 64 + threadIdx.x;
            batch_lds[threadIdx.x] = gr < M ? batch[gr] : -1;
        }
    }

    const unsigned short* zrow = Z + (size_t)rowc * K1 + q * 8;
    const unsigned short* wfl1 = Wf1 + lane * 8;
    const unsigned short* wfl2 = Wf2 + lane * 8;

    f32x4 acc[8];
#pragma unroll
    for (int t = 0; t < 8; t++) acc[t] = (f32x4)(0.0f);

    // phase 1: mid = Z @ W1
#pragma unroll
    for (int c = 0; c < KC1; c++) {
        bf16x8 a = *reinterpret_cast<const bf16x8*>(zrow + c * 32);
#pragma unroll
        for (int t = 0; t < 8; t++) {
            bf16x8 b = *reinterpret_cast<const bf16x8*>(wfl1 + ((t * KC1 + c) << 9));
            acc[t] = __builtin_amdgcn_mfma_f32_16x16x32_bf16(a, b, acc[t], 0, 0, 0);
        }
    }

    // epilogue 1: +b1, relu, hi/lo split -> LDS
#pragma unroll
    for (int r = 0; r < 4; r++) {
        int lr = wave * 16 + q * 4 + r;
#pragma unroll
        for (int t = 0; t < 8; t++) {
            int col = t * 16 + m_;
            float bv = flag ? ((const float*)bias1)[col]
                            : b2f(((const unsigned short*)bias1)[col]);
            float v = acc[t][r] + bv;
            v = v > 0.0f ? v : 0.0f;
            unsigned short hb = f2b(v);
            lds_hi[lr * 136 + col] = hb;
            lds_lo[lr * 136 + col] = f2b(v - b2f(hb));
        }
    }

#pragma unroll
    for (int t = 0; t < 8; t++) acc[t] = (f32x4)(0.0f);

    // phase 2: h = mid @ W2 (hi/lo from LDS)
    int lr2 = wave * 16 + m_;
#pragma unroll
    for (int c = 0; c < 4; c++) {
        bf16x8 ahi = *reinterpret_cast<const bf16x8*>(&lds_hi[lr2 * 136 + c * 32 + q * 8]);
        bf16x8 alo = *reinterpret_cast<const bf16x8*>(&lds_lo[lr2 * 136 + c * 32 + q * 8]);
#pragma unroll
        for (int t = 0; t < 8; t++) {
            bf16x8 b = *reinterpret_cast<const bf16x8*>(wfl2 + ((t * 4 + c) << 9));
            acc[t] = __builtin_amdgcn_mfma_f32_16x16x32_bf16(ahi, b, acc[t], 0, 0, 0);
            acc[t] = __builtin_amdgcn_mfma_f32_16x16x32_bf16(alo, b, acc[t], 0, 0, 0);
        }
    }

    // epilogue 2
#pragma unroll
    for (int r = 0; r < 4; r++) {
        int lr = wave * 16 + q * 4 + r;
        int orow = blockIdx.x * 64 + lr;
#pragma unroll
        for (int t = 0; t < 8; t++) {
            int col = t * 16 + m_;
            float bv = flag ? ((const float*)bias2)[col]
                            : b2f(((const unsigned short*)bias2)[col]);
            float v = acc[t][r] + bv;
            v = v > 0.0f ? v : 0.0f;
            if constexpr (POOL) {
                lds_hi[lr * 136 + col] = f2b(v);   // safe: own rows' phase-2 reads done
            } else {
                if (orow < M) Out[(size_t)orow * HID + col] = f2b(v);
            }
        }
    }

    if constexpr (POOL) {
        __syncthreads();
        int f = threadIdx.x;
        if (f < HID) {
            int cur = -1;
            float sum = 0.0f, mx = 0.0f;
            for (int rrow = 0; rrow < 64; rrow++) {
                int g = batch_lds[rrow];
                if (g < 0) break;   // tail padding
                float v = b2f(lds_hi[rrow * 136 + f]);
                if (g == cur) {
                    sum += v;
                    mx = fmaxf(mx, v);
                } else {
                    if (cur >= 0) {
                        atomicAdd(&psum[cur * HID + f], sum);
                        atomicMax(&pmax[cur * HID + f], __float_as_uint(mx));
                    }
                    cur = g; sum = v; mx = v;
                }
            }
            if (cur >= 0) {
                atomicAdd(&psum[cur * HID + f], sum);
                atomicMax(&pmax[cur * HID + f], __float_as_uint(mx));
            }
        }
    }
}

// ---------------- head: w1t[n][k] bf16 rows -> vectorized, unrolled dot ----------------
__global__ __launch_bounds__(128) void head_kernel(
    const float* __restrict__ psum, const unsigned int* __restrict__ pmax,
    const int* __restrict__ gstart,
    const unsigned short* __restrict__ w1t,
    const void* __restrict__ b1, const void* __restrict__ w2,
    const void* __restrict__ b2,
    void* __restrict__ out, const int* __restrict__ flagp) {
    int g = blockIdx.x;
    int n = threadIdx.x;
    int flag = *flagp;
    __shared__ float repr[2 * HID];
    __shared__ float red[HID];

    float c = (float)(gstart[g + 1] - gstart[g]);
    float inv = 1.0f / fmaxf(c, 1.0f);
    repr[n]       = psum[g * HID + n] * inv;
    repr[HID + n] = __uint_as_float(pmax[g * HID + n]);
    __syncthreads();

    const u16x8* wp = (const u16x8*)(w1t + n * 256);
    float a0 = 0.f, a1 = 0.f, a2 = 0.f, a3 = 0.f;
#pragma unroll
    for (int c8 = 0; c8 < 32; c8 += 4) {
        u16x8 w0 = wp[c8 + 0];
        u16x8 w1 = wp[c8 + 1];
        u16x8 w2v = wp[c8 + 2];
        u16x8 w3 = wp[c8 + 3];
#pragma unroll
        for (int j = 0; j < 8; j++) {
            a0 += repr[(c8 + 0) * 8 + j] * b2f(w0[j]);
            a1 += repr[(c8 + 1) * 8 + j] * b2f(w1[j]);
            a2 += repr[(c8 + 2) * 8 + j] * b2f(w2v[j]);
            a3 += repr[(c8 + 3) * 8 + j] * b2f(w3[j]);
        }
    }
    float b1v = flag ? ((const float*)b1)[n] : b2f(((const unsigned short*)b1)[n]);
    float acc = a0 + a1 + a2 + a3 + b1v;
    acc = fmaxf(acc, 0.0f);

    float w2s = flag ? ((const float*)w2)[n] : b2f(((const unsigned short*)w2)[n]);
    red[n] = acc * w2s;
    __syncthreads();
    for (int s = 64; s > 0; s >>= 1) {
        if (n < s) red[n] += red[n + s];
        __syncthreads();
    }
    if (n == 0) {
        float b2v = flag ? ((const float*)b2)[0] : b2f(((const unsigned short*)b2)[0]);
        float logit = red[0] + b2v;
        float sv = 1.0f / (1.0f + expf(-logit));
        if (flag) ((float*)out)[g] = sv;
        else      ((unsigned short*)out)[g] = f2b(sv);
    }
}

extern "C" void kernel_launch(void* const* d_in, const int* in_sizes, int n_in,
                              void* d_out, int out_size, void* d_ws, size_t ws_size,
                              hipStream_t stream) {
    const int* edge = (const int*)d_in[1];
    const int* srcv = edge;
    const int* dstv = edge + N_EDGES;
    const int* batch = (const int*)d_in[2];

    char* ws = (char*)d_ws;
    unsigned short* A = (unsigned short*)ws;               // 12.8 MB bf16 h (even)
    unsigned short* B = (unsigned short*)(ws + 12800000);  // 12.8 MB bf16 z / h (odd)
    unsigned int* ebuf = (unsigned int*)(ws + 25600000);   // 6.43 MB bucketed edges
    unsigned short* csr = (unsigned short*)(ws + 32100000);// 1.6 MB
    int* off    = (int*)(ws + 33700000);                   // 50001 ints
    unsigned short* wfbase = (unsigned short*)(ws + 33904000);  // 6 x 32 KB
    float* psum  = (float*)(ws + 34100608);                // 128 KB
    unsigned int* pmax = (unsigned int*)(ws + 34231680);   // 128 KB
    int* bcursor = (int*)(ws + 34362752);                  // 1 KB
    int* gstart  = (int*)(ws + 34363776);                  // 2 KB
    int* flagp   = (int*)(ws + 34365824);
    unsigned short* w1t = (unsigned short*)(ws + 34366848); // 64 KB

    const size_t NEED = 34500000;
    if (ws_size < NEED) {
        unsigned int k = 0;
        while ((((size_t)1) << (k + 1)) <= ws_size && k < 62) k++;
        diag_kernel<<<1, 256, 0, stream>>>((unsigned short*)d_out,
                                           (unsigned short)(0x4000 | (k & 63)));
        return;
    }

    mega_pre_kernel<<<581, 256, 0, stream>>>(
        (const unsigned short*)d_in[0],
        d_in[3], d_in[5], d_in[7], d_in[9], d_in[11], d_in[13], wfbase,
        batch, gstart, psum, pmax, d_in[15], w1t, bcursor, flagp);

    // CSR build: scatter into fixed buckets, then per-bucket sort (no bscan pass)
    const int EB = (N_EDGES + 4095) / 4096;   // 196
    bscatter_kernel<<<EB, 1024, 0, stream>>>(srcv, dstv, bcursor, ebuf);
    bsort_kernel<<<NBUCK, 256, 0, stream>>>(ebuf, bcursor, off, csr);

    const int GEMM_GRID = (N_NODES + 63) / 64;   // 782
    const int GATHER_GRID = N_NODES / 16;        // 3125 (exact)

    // layer 0: 64 -> 128 (x -> B(z) -> A(h1))
    gather_x_kernel<<<GATHER_GRID, 256, 0, stream>>>(d_in[0], off, csr, B, flagp);
    gin_mlp_kernel<64, false><<<GEMM_GRID, 256, 0, stream>>>(
        B, wfbase + 0 * 16384, d_in[4], wfbase + 1 * 16384, d_in[6],
        A, N_NODES, flagp, batch, psum, pmax);

    // layer 1: 128 -> 128 (A -> B(z) -> A)
    gather128_kernel<<<GATHER_GRID, 256, 0, stream>>>(A, off, csr, B);
    gin_mlp_kernel<128, false><<<GEMM_GRID, 256, 0, stream>>>(
        B, wfbase + 2 * 16384, d_in[8], wfbase + 3 * 16384, d_in[10],
        A, N_NODES, flagp, batch, psum, pmax);

    // layer 2: 128 -> 128 (A -> B(z) -> pooled directly, no h3 store)
    gather128_kernel<<<GATHER_GRID, 256, 0, stream>>>(A, off, csr, B);
    gin_mlp_kernel<128, true><<<GEMM_GRID, 256, 0, stream>>>(
        B, wfbase + 4 * 16384, d_in[12], wfbase + 5 * 16384, d_in[14],
        A /*unused*/, N_NODES, flagp, batch, psum, pmax);

    // head
    head_kernel<<<NUM_GRAPHS, 128, 0, stream>>>(psum, pmax, gstart, w1t,
                                                d_in[16], d_in[17], d_in[18],
                                                d_out, flagp);
}